// Round 7
// baseline (1833.223 us; speedup 1.0000x reference)
//
#include <hip/hip_runtime.h>

#define T_STEPS 1000
#define NIN     128
#define NREC    512
#define NBATCH  64
#define ALPHA   0.2f

#define NSLICE  4          // blocks per batch element (proven admission, r4)
#define SCOLS   128        // columns per slice (512/4)
#define NGRP    8          // k-groups per block (1024 threads / 128)
#define KPER    64         // k elements per group (= one h sub-slice)

// d_ws layout (bytes):
//   [0, 1MB)        W_eff (512x512 fp32)
//   [1MB, +512KB)   comm: 2 parities x 64 batches x 512 u64 {tag,h}
#define WS_W_OFF     0
#define WS_COMM_OFF  (1u << 20)
#define COMM_U64     (NBATCH * NREC)               // u64 elements per parity
#define WS_NEEDED    (WS_COMM_OFF + 2 * COMM_U64 * 8)

// LDS-only barrier: drains LDS ops, NOT vmcnt -- global ops stay in flight
// (comm visibility is the tag-protocol's job; io slots are thread-private).
#define LDS_BARRIER() do {                                        \
    asm volatile("s_waitcnt lgkmcnt(0)" ::: "memory");            \
    __builtin_amdgcn_s_barrier();                                 \
    asm volatile("" ::: "memory");                                \
} while (0)

// ---------------------------------------------------------------------------
// W_eff[k][j] = ei[k] * w_rec[k][j] * autapse[k][j]
// ---------------------------------------------------------------------------
__global__ void weff_kernel(const float* __restrict__ w_rec,
                            const float* __restrict__ ei_mask,
                            const float* __restrict__ autapse,
                            float* __restrict__ w_eff) {
    int idx = blockIdx.x * blockDim.x + threadIdx.x;
    if (idx < NREC * NREC) {
        int row = idx >> 9;
        float ei = ei_mask[row * NREC + row];
        w_eff[idx] = ei * w_rec[idx] * autapse[idx];
    }
}

// ---------------------------------------------------------------------------
// inp_all[m][j] = sum_k x[m][k] * w_in[k][j] + b_rec[j]   (into d_out)
// ---------------------------------------------------------------------------
__global__ __launch_bounds__(1024) void gemm_in_kernel(
        const float* __restrict__ x,
        const float* __restrict__ w_in,
        const float* __restrict__ b_rec,
        float* __restrict__ io) {
    __shared__ float xs[32][NIN];

    const int tid = threadIdx.x;
    const int m0  = blockIdx.x * 32;

    {
        const float4* src = reinterpret_cast<const float4*>(x + (size_t)m0 * NIN);
        reinterpret_cast<float4*>(&xs[0][0])[tid] = src[tid];
    }
    __syncthreads();

    const int j0 = tid & 255;
    const int j1 = j0 + 256;
    const int rg = tid >> 8;

    float acc[8][2];
#pragma unroll
    for (int i = 0; i < 8; ++i) { acc[i][0] = 0.f; acc[i][1] = 0.f; }

#pragma unroll 4
    for (int k = 0; k < NIN; ++k) {
        float wv0 = w_in[k * NREC + j0];
        float wv1 = w_in[k * NREC + j1];
#pragma unroll
        for (int i = 0; i < 8; ++i) {
            float xv = xs[rg * 8 + i][k];
            acc[i][0] = fmaf(xv, wv0, acc[i][0]);
            acc[i][1] = fmaf(xv, wv1, acc[i][1]);
        }
    }

    const float br0 = b_rec[j0];
    const float br1 = b_rec[j1];
#pragma unroll
    for (int i = 0; i < 8; ++i) {
        size_t ro = (size_t)(m0 + rg * 8 + i) * NREC;
        io[ro + j0] = acc[i][0] + br0;
        io[ro + j1] = acc[i][1] + br1;
    }
}

// ---------------------------------------------------------------------------
// Cooperative recurrence, single-barrier pipelined.
// 256 blocks (batch b = blk>>2, slice s = blk&3), 1024 threads
// (jl = tid&127 column, g = tid>>7 k-group, ln = tid&63).
// Thread (g,jl) holds W[g*64..+64)[s*128+jl] (AGPR-resident, free on gfx950).
// Window t:  issue poll(tag>=t, parity t&1)
//            leaders (tid<128): finish step t-1 from part[parity^1], store
//              {tag=t, h_t} payload + io row t-1, prefetch inp/noise for t
//            poll-wait; stage h slice into LDS (per-wave, 64 slots);
//            64-fmaf partial dot; write part[parity]; ONE lgkm-only barrier.
// ALL groups (own included) get h via the comm payload -> no second barrier.
// Deadlock-free: every block stores tag t before waiting on tag t.
// ---------------------------------------------------------------------------
__global__ __launch_bounds__(1024, 4) void rnn_coop(
        const float* __restrict__ W,
        const float* __restrict__ noise,
        float* __restrict__ io,
        unsigned long long* __restrict__ comm) {
    __shared__ __align__(16) float h_stage[NREC];     // [g*64, +64) per group
    __shared__ float part[2][NGRP * SCOLS];           // parity double-buffer

    const int tid = threadIdx.x;
    const int b   = blockIdx.x >> 2;
    const int s   = blockIdx.x & 3;
    const int jl  = tid & (SCOLS - 1);
    const int g   = tid >> 7;              // 0..7
    const int ln  = tid & 63;
    const int jg  = s * SCOLS + jl;

    // one-time W slice load (coalesced); pin against remat-reload
    float Wr[KPER];
    {
        const float* wp = W + (size_t)(g * KPER) * NREC + jg;
#pragma unroll
        for (int u = 0; u < KPER; ++u)
            Wr[u] = wp[(size_t)u * NREC];
    }
#pragma unroll
    for (int u = 0; u < KPER; ++u)
        asm volatile("" : "+v"(Wr[u]));

    float hj = 0.f;                        // leaders' (tid<128) own h state
    const size_t iobase = (size_t)b * T_STEPS * NREC + jg;
    const unsigned long long* cbase = comm + (size_t)b * NREC + g * KPER + ln;
    unsigned long long* cwbase = comm + (size_t)b * NREC + jg;

    // preload step 0's input projection + noise (leaders; used in window 1)
    float inp = 0.f, nz = 0.f;
    if (tid < SCOLS) { inp = io[iobase]; nz = noise[iobase]; }

    for (int t = 0; t < T_STEPS; ++t) {
        const int p = t & 1;

        // (1) issue this window's poll load early (flight hides leader phase)
        const unsigned long long* cp = cbase + (size_t)p * COMM_U64;
        unsigned long long v = __hip_atomic_load(
            cp, __ATOMIC_RELAXED, __HIP_MEMORY_SCOPE_AGENT);

        // (2) leaders finish step t-1: h_t = update(h_{t-1}, part[p^1])
        if (t > 0 && tid < SCOLS) {
            float pre = inp + nz;
#pragma unroll
            for (int q = 0; q < NGRP; ++q)
                pre += part[p ^ 1][q * SCOLS + jl];
            float hnew = (1.f - ALPHA) * hj + ALPHA * fmaxf(pre, 0.f);
            hj = hnew;
            unsigned long long pv =
                ((unsigned long long)(unsigned)t << 32) |
                (unsigned long long)__float_as_uint(hnew);
            __hip_atomic_store(cwbase + (size_t)p * COMM_U64, pv,
                               __ATOMIC_RELAXED, __HIP_MEMORY_SCOPE_AGENT);
            io[iobase + (size_t)(t - 1) * NREC] = hnew;   // trajectory row t-1
            inp = io[iobase + (size_t)t * NREC];          // prefetch step t
            nz  = noise[iobase + (size_t)t * NREC];
        }

        // (3) wait for h_t of slice g (tag >= t)
        while ((int)(unsigned)(v >> 32) < t)
            v = __hip_atomic_load(cp, __ATOMIC_RELAXED,
                                  __HIP_MEMORY_SCOPE_AGENT);
        asm volatile("" ::: "memory");
        // each wave writes the full 64-slot range it reads (redundant twin ok)
        h_stage[g * KPER + ln] = __uint_as_float((unsigned)(v & 0xffffffffu));

        // (4) 64-long partial dot (plain fmaf: compiler batches ds_reads)
        float a0 = 0.f, a1 = 0.f, a2 = 0.f, a3 = 0.f;
        const float4* h4 = reinterpret_cast<const float4*>(&h_stage[g * KPER]);
#pragma unroll
        for (int u = 0; u < KPER / 4; ++u) {
            float4 hv = h4[u];
            a0 = fmaf(hv.x, Wr[4 * u + 0], a0);
            a1 = fmaf(hv.y, Wr[4 * u + 1], a1);
            a2 = fmaf(hv.z, Wr[4 * u + 2], a2);
            a3 = fmaf(hv.w, Wr[4 * u + 3], a3);
        }
        part[p][g * SCOLS + jl] = (a0 + a1) + (a2 + a3);

        LDS_BARRIER();                     // the ONLY barrier per window
    }

    // epilogue: leaders finish step T-1 -> io row T-1 (no comm store needed)
    if (tid < SCOLS) {
        const int pe = (T_STEPS - 1) & 1;
        float pre = inp + nz;
#pragma unroll
        for (int q = 0; q < NGRP; ++q)
            pre += part[pe][q * SCOLS + jl];
        float hnew = (1.f - ALPHA) * hj + ALPHA * fmaxf(pre, 0.f);
        io[iobase + (size_t)(T_STEPS - 1) * NREC] = hnew;
    }
}

// ---------------------------------------------------------------------------
// Fallback (round-1 kernel) if ws_size is too small for comm buffers.
// ---------------------------------------------------------------------------
__global__ __launch_bounds__(1024) void rnn_kernel(
        const float* __restrict__ W,
        const float* __restrict__ noise,
        float* __restrict__ io) {
    __shared__ float h[NREC];
    __shared__ float part2[NREC];

    const int tid  = threadIdx.x;
    const int j    = tid & (NREC - 1);
    const int half = tid >> 9;
    const int b    = blockIdx.x;

    if (tid < NREC) h[tid] = 0.f;
    float hj = 0.f;
    __syncthreads();

    const int kb = half * 256;
    const float* wp = W + (size_t)kb * NREC + j;
    const size_t base = (size_t)b * T_STEPS * NREC + j;

    for (int t = 0; t < T_STEPS; ++t) {
        const size_t off = base + (size_t)t * NREC;
        float acc = (half == 0) ? (io[off] + noise[off]) : 0.f;
#pragma unroll
        for (int ku = 0; ku < 256; ku += 16) {
            float w[16];
#pragma unroll
            for (int u = 0; u < 16; ++u) w[u] = wp[(size_t)(ku + u) * NREC];
#pragma unroll
            for (int u = 0; u < 16; ++u) acc = fmaf(h[kb + ku + u], w[u], acc);
        }
        if (half == 1) part2[j] = acc;
        __syncthreads();
        if (half == 0) {
            float pre  = acc + part2[j];
            float hnew = (1.f - ALPHA) * hj + ALPHA * fmaxf(pre, 0.f);
            io[off] = hnew;
            h[j] = hnew;
            hj = hnew;
        }
        __syncthreads();
    }
}

// ---------------------------------------------------------------------------
extern "C" void kernel_launch(void* const* d_in, const int* in_sizes, int n_in,
                              void* d_out, int out_size, void* d_ws, size_t ws_size,
                              hipStream_t stream) {
    const float* x       = (const float*)d_in[0];
    const float* w_in    = (const float*)d_in[1];
    const float* w_rec   = (const float*)d_in[2];
    const float* b_rec   = (const float*)d_in[3];
    const float* ei_mask = (const float*)d_in[4];
    const float* autapse = (const float*)d_in[5];
    const float* noise   = (const float*)d_in[6];
    float* out = (float*)d_out;

    char* ws = (char*)d_ws;
    float* W = (float*)(ws + WS_W_OFF);
    unsigned long long* comm = (unsigned long long*)(ws + WS_COMM_OFF);

    weff_kernel<<<dim3((NREC * NREC + 255) / 256), dim3(256), 0, stream>>>(
        w_rec, ei_mask, autapse, W);

    gemm_in_kernel<<<dim3(64000 / 32), dim3(1024), 0, stream>>>(
        x, w_in, b_rec, out);

    if (ws_size >= (size_t)WS_NEEDED) {
        hipMemsetAsync(comm, 0, 2 * COMM_U64 * 8, stream);   // reset tags
        void* args[] = {(void*)&W, (void*)&noise, (void*)&out, (void*)&comm};
        hipLaunchCooperativeKernel(reinterpret_cast<void*>(rnn_coop),
                                   dim3(NBATCH * NSLICE), dim3(1024),
                                   args, 0, stream);
    } else {
        rnn_kernel<<<dim3(NBATCH), dim3(1024), 0, stream>>>(W, noise, out);
    }
}

// Round 9
// 1675.079 us; speedup vs baseline: 1.0944x; 1.0944x over previous
//
#include <hip/hip_runtime.h>

#define T_STEPS 1000
#define NIN     128
#define NREC    512
#define NBATCH  64
#define ALPHA   0.2f

#define NSLICE  4          // blocks per batch element (proven geometry, r4)
#define SCOLS   128        // columns per slice (512/4)
#define NGRP    8          // k-groups per block (1024 threads / 128)
#define KPER    64         // k elements per group

// d_ws layout (bytes):
//   [0, 1MB)        W_eff (512x512 fp32)
//   [1MB, +512KB)   comm: 2 parities x 64 batches x 512 u64 {tag,h}
#define WS_W_OFF     0
#define WS_COMM_OFF  (1u << 20)
#define COMM_U64     (NBATCH * NREC)               // u64 elements per parity
#define WS_NEEDED    (WS_COMM_OFF + 2 * COMM_U64 * 8)

// LDS-only barrier: drains LDS ops, NOT vmcnt. Global loads/stores stay in
// flight across it: comm visibility is the tag-protocol's job (payload polled
// until tag arrives), io slots are thread-private, prefetch loads are
// consumed via normal compiler-inserted vmcnt waits at use. "memory"
// clobbers on both sides fence compiler code motion of LDS accesses.
// (Correctness-proven in r6/r7 runs, absmax 0.0078.)
#define LDS_BARRIER() do {                                        \
    asm volatile("s_waitcnt lgkmcnt(0)" ::: "memory");            \
    __builtin_amdgcn_s_barrier();                                 \
    asm volatile("" ::: "memory");                                \
} while (0)

// ---------------------------------------------------------------------------
// W_eff[k][j] = ei[k] * w_rec[k][j] * autapse[k][j]
// ---------------------------------------------------------------------------
__global__ void weff_kernel(const float* __restrict__ w_rec,
                            const float* __restrict__ ei_mask,
                            const float* __restrict__ autapse,
                            float* __restrict__ w_eff) {
    int idx = blockIdx.x * blockDim.x + threadIdx.x;
    if (idx < NREC * NREC) {
        int row = idx >> 9;
        float ei = ei_mask[row * NREC + row];
        w_eff[idx] = ei * w_rec[idx] * autapse[idx];
    }
}

// ---------------------------------------------------------------------------
// inp_all[m][j] = sum_k x[m][k] * w_in[k][j] + b_rec[j]   (into d_out)
// ---------------------------------------------------------------------------
__global__ __launch_bounds__(1024) void gemm_in_kernel(
        const float* __restrict__ x,
        const float* __restrict__ w_in,
        const float* __restrict__ b_rec,
        float* __restrict__ io) {
    __shared__ float xs[32][NIN];

    const int tid = threadIdx.x;
    const int m0  = blockIdx.x * 32;

    {
        const float4* src = reinterpret_cast<const float4*>(x + (size_t)m0 * NIN);
        reinterpret_cast<float4*>(&xs[0][0])[tid] = src[tid];
    }
    __syncthreads();

    const int j0 = tid & 255;
    const int j1 = j0 + 256;
    const int rg = tid >> 8;

    float acc[8][2];
#pragma unroll
    for (int i = 0; i < 8; ++i) { acc[i][0] = 0.f; acc[i][1] = 0.f; }

#pragma unroll 4
    for (int k = 0; k < NIN; ++k) {
        float wv0 = w_in[k * NREC + j0];
        float wv1 = w_in[k * NREC + j1];
#pragma unroll
        for (int i = 0; i < 8; ++i) {
            float xv = xs[rg * 8 + i][k];
            acc[i][0] = fmaf(xv, wv0, acc[i][0]);
            acc[i][1] = fmaf(xv, wv1, acc[i][1]);
        }
    }

    const float br0 = b_rec[j0];
    const float br1 = b_rec[j1];
#pragma unroll
    for (int i = 0; i < 8; ++i) {
        size_t ro = (size_t)(m0 + rg * 8 + i) * NREC;
        io[ro + j0] = acc[i][0] + br0;
        io[ro + j1] = acc[i][1] + br1;
    }
}

// ---------------------------------------------------------------------------
// Cooperative recurrence -- EXACT round-4 structure (1.61 ms proven:
// 256 blocks x 1024 thr, u64 {tag,h} payload comm, own slice via LDS,
// plain fmaf, 2-wave leaders) with ONE change: the two in-loop
// __syncthreads() are now lgkm-only barriers, so the leaders' comm/io
// stores and the next-step HBM prefetch loads are no longer drained at
// every barrier -- their latency overlaps the next window.
// ---------------------------------------------------------------------------
__global__ __launch_bounds__(1024, 4) void rnn_coop(
        const float* __restrict__ W,
        const float* __restrict__ noise,
        float* __restrict__ io,
        unsigned long long* __restrict__ comm) {
    __shared__ __align__(16) float h_lds[NREC];
    __shared__ float part[NGRP * SCOLS];

    const int tid = threadIdx.x;
    const int b   = blockIdx.x >> 2;
    const int s   = blockIdx.x & 3;
    const int jl  = tid & (SCOLS - 1);
    const int g   = tid >> 7;              // 0..7
    const int ln  = tid & 63;
    const int jg  = s * SCOLS + jl;
    const bool remote = (g >> 1) != s;     // this k-group's h slice is remote
    const int cslot = g * KPER + ln;       // h index this lane gathers

    // one-time W slice load (coalesced), then pin (AGPR-resident is fine on
    // gfx950's unified file -- direct MFMA/VALU operand reads)
    float Wr[KPER];
    {
        const float* wp = W + (size_t)(g * KPER) * NREC + jg;
#pragma unroll
        for (int u = 0; u < KPER; ++u)
            Wr[u] = wp[(size_t)u * NREC];
    }
#pragma unroll
    for (int u = 0; u < KPER; ++u)
        asm volatile("" : "+v"(Wr[u]));

    if (tid < NREC) h_lds[tid] = 0.f;
    __syncthreads();

    float hj = 0.f;                        // leaders' (tid<128) own h
    const size_t iobase = (size_t)b * T_STEPS * NREC + jg;
    const unsigned long long* cbase = comm + (size_t)b * NREC + cslot;
    unsigned long long* cwbase = comm + (size_t)b * NREC + jg;

    // prefetch step 0's input projection + noise (leaders)
    float inp = 0.f, nz = 0.f;
    if (tid < SCOLS) { inp = io[iobase]; nz = noise[iobase]; }

    for (int t = 0; t < T_STEPS; ++t) {
        const size_t off = iobase + (size_t)t * NREC;

        // issue NEXT step's loads now (slot (b,t+1,jg) is written only by
        // this same thread, at step t+1 -> program-order safe)
        float inp_n = 0.f, nz_n = 0.f;
        if (t + 1 < T_STEPS && tid < SCOLS) {
            inp_n = io[off + NREC];
            nz_n  = noise[off + NREC];
        }

        if (t > 0 && remote) {
            const unsigned long long* cp = cbase + (size_t)(t & 1) * COMM_U64;
            unsigned long long v = __hip_atomic_load(
                cp, __ATOMIC_RELAXED, __HIP_MEMORY_SCOPE_AGENT);
            while ((int)(unsigned)(v >> 32) < t)
                v = __hip_atomic_load(cp, __ATOMIC_RELAXED,
                                      __HIP_MEMORY_SCOPE_AGENT);
            asm volatile("" ::: "memory");
            // both waves of group g write the same 64 slots w/ same value
            h_lds[cslot] = __uint_as_float((unsigned)(v & 0xffffffffu));
        }

        // 64-long partial dot (plain fmaf: compiler batches the ds_reads)
        float a0 = 0.f, a1 = 0.f, a2 = 0.f, a3 = 0.f;
        const float4* h4 = reinterpret_cast<const float4*>(&h_lds[g * KPER]);
#pragma unroll
        for (int u = 0; u < KPER / 4; ++u) {
            float4 hv = h4[u];
            a0 = fmaf(hv.x, Wr[4 * u + 0], a0);
            a1 = fmaf(hv.y, Wr[4 * u + 1], a1);
            a2 = fmaf(hv.z, Wr[4 * u + 2], a2);
            a3 = fmaf(hv.w, Wr[4 * u + 3], a3);
        }
        part[g * SCOLS + jl] = (a0 + a1) + (a2 + a3);
        LDS_BARRIER();                                 // B1: partials ready

        if (tid < SCOLS) {                             // leader waves 0,1
            float pre = inp + nz;
#pragma unroll
            for (int q = 0; q < NGRP; ++q)
                pre += part[q * SCOLS + jl];
            float hnew = (1.f - ALPHA) * hj + ALPHA * fmaxf(pre, 0.f);
            hj = hnew;
            h_lds[jg] = hnew;                          // own slice for t+1
            unsigned long long pv =
                ((unsigned long long)(unsigned)(t + 1) << 32) |
                (unsigned long long)__float_as_uint(hnew);
            __hip_atomic_store(cwbase + (size_t)((t + 1) & 1) * COMM_U64, pv,
                               __ATOMIC_RELAXED, __HIP_MEMORY_SCOPE_AGENT);
            io[off] = hnew;                            // trajectory output
        }
        inp = inp_n; nz = nz_n;
        LDS_BARRIER();                                 // B2: h_lds ready
    }
}

// ---------------------------------------------------------------------------
// Fallback (round-1 kernel) if ws_size is too small for comm buffers.
// ---------------------------------------------------------------------------
__global__ __launch_bounds__(1024) void rnn_kernel(
        const float* __restrict__ W,
        const float* __restrict__ noise,
        float* __restrict__ io) {
    __shared__ float h[NREC];
    __shared__ float part2[NREC];

    const int tid  = threadIdx.x;
    const int j    = tid & (NREC - 1);
    const int half = tid >> 9;
    const int b    = blockIdx.x;

    if (tid < NREC) h[tid] = 0.f;
    float hj = 0.f;
    __syncthreads();

    const int kb = half * 256;
    const float* wp = W + (size_t)kb * NREC + j;
    const size_t base = (size_t)b * T_STEPS * NREC + j;

    for (int t = 0; t < T_STEPS; ++t) {
        const size_t off = base + (size_t)t * NREC;
        float acc = (half == 0) ? (io[off] + noise[off]) : 0.f;
#pragma unroll
        for (int ku = 0; ku < 256; ku += 16) {
            float w[16];
#pragma unroll
            for (int u = 0; u < 16; ++u) w[u] = wp[(size_t)(ku + u) * NREC];
#pragma unroll
            for (int u = 0; u < 16; ++u) acc = fmaf(h[kb + ku + u], w[u], acc);
        }
        if (half == 1) part2[j] = acc;
        __syncthreads();
        if (half == 0) {
            float pre  = acc + part2[j];
            float hnew = (1.f - ALPHA) * hj + ALPHA * fmaxf(pre, 0.f);
            io[off] = hnew;
            h[j] = hnew;
            hj = hnew;
        }
        __syncthreads();
    }
}

// ---------------------------------------------------------------------------
extern "C" void kernel_launch(void* const* d_in, const int* in_sizes, int n_in,
                              void* d_out, int out_size, void* d_ws, size_t ws_size,
                              hipStream_t stream) {
    const float* x       = (const float*)d_in[0];
    const float* w_in    = (const float*)d_in[1];
    const float* w_rec   = (const float*)d_in[2];
    const float* b_rec   = (const float*)d_in[3];
    const float* ei_mask = (const float*)d_in[4];
    const float* autapse = (const float*)d_in[5];
    const float* noise   = (const float*)d_in[6];
    float* out = (float*)d_out;

    char* ws = (char*)d_ws;
    float* W = (float*)(ws + WS_W_OFF);
    unsigned long long* comm = (unsigned long long*)(ws + WS_COMM_OFF);

    weff_kernel<<<dim3((NREC * NREC + 255) / 256), dim3(256), 0, stream>>>(
        w_rec, ei_mask, autapse, W);

    gemm_in_kernel<<<dim3(64000 / 32), dim3(1024), 0, stream>>>(
        x, w_in, b_rec, out);

    if (ws_size >= (size_t)WS_NEEDED) {
        hipMemsetAsync(comm, 0, 2 * COMM_U64 * 8, stream);   // reset tags
        void* args[] = {(void*)&W, (void*)&noise, (void*)&out, (void*)&comm};
        hipLaunchCooperativeKernel(reinterpret_cast<void*>(rnn_coop),
                                   dim3(NBATCH * NSLICE), dim3(1024),
                                   args, 0, stream);
    } else {
        rnn_kernel<<<dim3(NBATCH), dim3(1024), 0, stream>>>(W, noise, out);
    }
}